// Round 3
// baseline (25572.476 us; speedup 1.0000x reference)
//
#include <hip/hip_runtime.h>
#include <hip/hip_cooperative_groups.h>

namespace cg = cooperative_groups;

constexpr int BATCH = 2, SEQL = 2048, DMODEL = 512, DINNER = 1024;
constexpr int DSTATE = 16, DTRANK = 32, NLAYER = 15, BLKSZ = 64;
constexpr int NCHUNK = 32, TT = 65, CONVK = 4;

// ---- workspace layout (float units). Total ~54.3 MB.
constexpr size_t SZ_H   = (size_t)BATCH*SEQL*DMODEL;      // 2,097,152
constexpr size_t SZ_ST  = (size_t)NLAYER*BATCH*DMODEL;
constexpr size_t SZ_MEM = (size_t)BATCH*NCHUNK*DMODEL;
constexpr size_t SZ_XZ1 = (size_t)BATCH*TT*2*DINNER;
constexpr size_t SZ_XC1 = (size_t)BATCH*TT*DINNER;
constexpr size_t SZ_XD1 = (size_t)BATCH*TT*64;
constexpr size_t OFF_H   = 0;
constexpr size_t OFF_ST  = OFF_H + SZ_H;
constexpr size_t OFF_MEM = OFF_ST + SZ_ST;
constexpr size_t OFF_XZ  = OFF_MEM + SZ_MEM;
constexpr size_t OFF_XC  = OFF_XZ + (size_t)NLAYER*SZ_XZ1;   // xc doubles as ym
constexpr size_t OFF_XD  = OFF_XC + (size_t)NLAYER*SZ_XC1;
constexpr size_t OFF_Q   = OFF_XD + (size_t)NLAYER*SZ_XD1;
constexpr size_t OFF_K   = OFF_Q + SZ_H;
constexpr size_t OFF_V   = OFF_K + SZ_MEM;
constexpr size_t OFF_AO  = OFF_V + SZ_MEM;                   // ao doubles as hres
constexpr size_t OFF_WT  = OFF_AO + SZ_H;                    // 4 x 262144 floats (W^T)

// ============================================================================
// Cooperative kernel: embedding + 2D wavefront over (chunk, layer) stages.
// ============================================================================
__global__ void __launch_bounds__(256, 1)
mamba_coop(const int* __restrict__ tokens, const float* __restrict__ embed,
           const float* __restrict__ rms_w, const float* __restrict__ W_in,
           const float* __restrict__ conv_w, const float* __restrict__ conv_b,
           const float* __restrict__ x_proj, const float* __restrict__ dt_w,
           const float* __restrict__ dt_b, const float* __restrict__ A_log,
           const float* __restrict__ D_skip, const float* __restrict__ W_out,
           const float* __restrict__ init_state, float* __restrict__ ws)
{
  cg::grid_group grid = cg::this_grid();
  __shared__ __align__(16) float lds[16384];   // 64 KB
  float* h_  = ws + OFF_H;
  float* st_ = ws + OFF_ST;
  float* memb = ws + OFF_MEM;
  const int wg = blockIdx.x, tid = threadIdx.x;
  const int wv = tid >> 6, ln = tid & 63;

  // ---------- Phase E: embedding gather + state init ----------
  {
    const int gtid = wg*256 + tid;
    for (int g = gtid; g < BATCH*SEQL*(DMODEL/8); g += 240*256) {
      const int bl = g >> 6;
      const int m0 = (g & 63) << 3;
      const int tok = tokens[bl];
      const float* ep = embed + (size_t)tok*DMODEL + m0;
      float* hp = h_ + (size_t)bl*DMODEL + m0;
      *(float4*)hp     = *(const float4*)ep;
      *(float4*)(hp+4) = *(const float4*)(ep+4);
    }
    for (int i = gtid; i < NLAYER*BATCH*DMODEL; i += 240*256) {
      const int m = i & (DMODEL-1);
      const int j = i / (BATCH*DMODEL);
      st_[i] = init_state[j*DMODEL + m];
    }
  }
  grid.sync();

  // ---------- wavefront over diagonals ----------
  for (int diag = 0; diag < NCHUNK + NLAYER - 1; ++diag) {
    const int c_lo = (diag - (NLAYER-1)) > 0 ? (diag - (NLAYER-1)) : 0;
    const int c_hi = diag < (NCHUNK-1) ? diag : (NCHUNK-1);
    const int nst = c_hi - c_lo + 1;
    const int sidx = wg % nst;
    const int swg  = wg / nst;
    const int nwg  = (239 - sidx)/nst + 1;   // #WGs on this stage (>=16 always)
    const int c = c_lo + sidx;
    const int j = diag - c;
    float* xz = ws + OFF_XZ + (size_t)j*SZ_XZ1;
    float* xc = ws + OFF_XC + (size_t)j*SZ_XC1;
    float* xd = ws + OFF_XD + (size_t)j*SZ_XD1;
    float* ym = xc;                          // ym aliases xc (in-place in P5)

    // ---------------- P1: xz = [state; rmsnorm(co)] @ W_in  (130x2048, K=512)
    {
      const float* Wi = W_in + (size_t)j*DMODEL*2*DINNER;
      const float* rw = rms_w + (size_t)j*DMODEL;
      for (int rt = 0; rt < 9; ++rt) {
        const int rmax = (130 - rt*16) < 16 ? (130 - rt*16) : 16;
        __syncthreads();
        for (int r = wv; r < rmax; r += 4) {
          const int m = rt*16 + r;
          const int b = m / TT, t = m - b*TT;
          const int k0 = ln*8;
          if (t == 0) {
            const float* src = st_ + ((size_t)j*BATCH + b)*DMODEL + k0;
            *(float4*)(lds + r*512 + k0)     = *(const float4*)src;
            *(float4*)(lds + r*512 + k0 + 4) = *(const float4*)(src+4);
          } else {
            const float* src = h_ + (size_t)(b*SEQL + c*BLKSZ + t-1)*DMODEL + k0;
            const float4 v0 = *(const float4*)src;
            const float4 v1 = *(const float4*)(src+4);
            float ss = v0.x*v0.x + v0.y*v0.y + v0.z*v0.z + v0.w*v0.w
                     + v1.x*v1.x + v1.y*v1.y + v1.z*v1.z + v1.w*v1.w;
            #pragma unroll
            for (int off = 32; off > 0; off >>= 1) ss += __shfl_xor(ss, off);
            const float rs = rsqrtf(ss * (1.f/512.f) + 1e-6f);
            const float o[8] = {v0.x,v0.y,v0.z,v0.w,v1.x,v1.y,v1.z,v1.w};
            #pragma unroll
            for (int x = 0; x < 8; ++x)
              lds[r*512 + k0 + x] = o[x] * rs * rw[k0 + x];
          }
        }
        __syncthreads();
        for (int ct = swg; ct < 16; ct += nwg) {
          const int col0 = ct*128 + (tid & 63)*2;
          const int rq = tid >> 6;
          const float2* wp2 = (const float2*)(Wi + col0);   // stride 1024 float2
          const float* ap = lds + rq*2048;
          float acc0[4] = {0,0,0,0}, acc1[4] = {0,0,0,0};
          for (int k = 0; k < 512; k += 4) {
            const float2 w0 = wp2[(size_t)(k+0)*1024];
            const float2 w1 = wp2[(size_t)(k+1)*1024];
            const float2 w2 = wp2[(size_t)(k+2)*1024];
            const float2 w3 = wp2[(size_t)(k+3)*1024];
            #pragma unroll
            for (int r4 = 0; r4 < 4; ++r4) {
              const float4 a = *(const float4*)(ap + r4*512 + k);
              acc0[r4] = fmaf(a.x, w0.x, acc0[r4]); acc1[r4] = fmaf(a.x, w0.y, acc1[r4]);
              acc0[r4] = fmaf(a.y, w1.x, acc0[r4]); acc1[r4] = fmaf(a.y, w1.y, acc1[r4]);
              acc0[r4] = fmaf(a.z, w2.x, acc0[r4]); acc1[r4] = fmaf(a.z, w2.y, acc1[r4]);
              acc0[r4] = fmaf(a.w, w3.x, acc0[r4]); acc1[r4] = fmaf(a.w, w3.y, acc1[r4]);
            }
          }
          #pragma unroll
          for (int r4 = 0; r4 < 4; ++r4) {
            const int m = rt*16 + rq*4 + r4;
            if (m < 130)
              *(float2*)(xz + (size_t)m*2048 + col0) = make_float2(acc0[r4], acc1[r4]);
          }
        }
      }
    }
    grid.sync();

    // ---------------- P3: conv+silu -> xc ; xdbl = xc @ x_proj (130x64, K=1024)
    {
      const float* cw  = conv_w + (size_t)j*DINNER*CONVK;
      const float* cbp = conv_b + (size_t)j*DINNER;
      const float* xpw = x_proj + (size_t)j*DINNER*64;
      for (int m = swg; m < 130; m += nwg) {
        const int b = m / TT, t = m - b*TT;
        __syncthreads();
        for (int d = tid; d < DINNER; d += 256) {
          float a = cbp[d];
          #pragma unroll
          for (int q = 0; q < CONVK; ++q) {
            const int ttk = t - 3 + q;
            if (ttk >= 0) a = fmaf(xz[(size_t)(b*TT+ttk)*2048 + d], cw[d*4+q], a);
          }
          const float sv = a / (1.f + __expf(-a));     // silu
          lds[d] = sv;
          xc[(size_t)(b*TT+t)*DINNER + d] = sv;
        }
        __syncthreads();
        {
          const int n = tid & 63, sl = tid >> 6;
          float p = 0.f;
          const float* wp = xpw + n;
          for (int k = sl*256; k < sl*256 + 256; k += 4) {
            const float4 a = *(const float4*)(lds + k);
            p = fmaf(a.x, wp[(size_t)(k+0)*64], p);
            p = fmaf(a.y, wp[(size_t)(k+1)*64], p);
            p = fmaf(a.z, wp[(size_t)(k+2)*64], p);
            p = fmaf(a.w, wp[(size_t)(k+3)*64], p);
          }
          lds[1024 + sl*64 + n] = p;
        }
        __syncthreads();
        if (tid < 64)
          xd[(size_t)m*64 + tid] = lds[1024+tid] + lds[1088+tid] + lds[1152+tid] + lds[1216+tid];
      }
    }
    grid.sync();

    // ---------------- P5: dt = softplus(xdbl[:,:32]@dt_w + dt_b); selective scan
    if (swg < 8) {
      const int sid = swg*256 + tid;
      const int b = sid >> 10, d = sid & 1023;
      for (int i = tid; i < TT*64; i += 256) lds[i] = xd[(size_t)b*TT*64 + i];
      __syncthreads();
      float dtwr[32];
      const float* dwp = dt_w + (size_t)j*DTRANK*DINNER + d;
      #pragma unroll
      for (int r = 0; r < 32; ++r) dtwr[r] = dwp[(size_t)r*DINNER];
      float Ai[16], s[16];
      const float* alp = A_log + (size_t)j*DINNER*DSTATE + (size_t)d*DSTATE;
      #pragma unroll
      for (int i = 0; i < 16; ++i) { Ai[i] = -__expf(alp[i]); s[i] = 0.f; }
      const float dtbv = dt_b[(size_t)j*DINNER + d];
      const float Dv   = D_skip[(size_t)j*DINNER + d];
      float* xcp = xc + (size_t)b*TT*DINNER + d;      // read x, then write y here
      const float* xzp = xz + (size_t)b*TT*2048 + DINNER + d;
      for (int t = 0; t < TT; ++t) {
        float4 xv[16];
        const float4* xr4 = (const float4*)(lds + t*64);
        #pragma unroll
        for (int i2 = 0; i2 < 16; ++i2) xv[i2] = xr4[i2];
        float dl = dtbv;
        #pragma unroll
        for (int r = 0; r < 8; ++r) {
          dl = fmaf(xv[r].x, dtwr[4*r+0], dl);
          dl = fmaf(xv[r].y, dtwr[4*r+1], dl);
          dl = fmaf(xv[r].z, dtwr[4*r+2], dl);
          dl = fmaf(xv[r].w, dtwr[4*r+3], dl);
        }
        const float e = __expf(dl);
        const float dtv = (dl > 15.f) ? dl : log1pf(e);   // softplus
        const float xcv = xcp[(size_t)t*DINNER];
        const float u = dtv * xcv;
        float yv = 0.f;
        #pragma unroll
        for (int i = 0; i < 4; ++i) {
          float P;
          P = __expf(dtv*Ai[4*i+0]); s[4*i+0] = fmaf(s[4*i+0], P, u*xv[8+i].x); yv = fmaf(s[4*i+0], xv[12+i].x, yv);
          P = __expf(dtv*Ai[4*i+1]); s[4*i+1] = fmaf(s[4*i+1], P, u*xv[8+i].y); yv = fmaf(s[4*i+1], xv[12+i].y, yv);
          P = __expf(dtv*Ai[4*i+2]); s[4*i+2] = fmaf(s[4*i+2], P, u*xv[8+i].z); yv = fmaf(s[4*i+2], xv[12+i].z, yv);
          P = __expf(dtv*Ai[4*i+3]); s[4*i+3] = fmaf(s[4*i+3], P, u*xv[8+i].w); yv = fmaf(s[4*i+3], xv[12+i].w, yv);
        }
        const float zv = xzp[(size_t)t*2048];
        const float sz = zv / (1.f + __expf(-zv));
        xcp[(size_t)t*DINNER] = (yv + Dv*xcv) * sz;   // ym in place of xc
      }
    }
    grid.sync();

    // ---------------- P6: lo = ym @ W_out (rows t=1..64); h += lo; state/mem
    if (swg < 16) {
      const int rt = swg & 7;        // 8 row tiles of 16 (128 rows)
      const int cth = swg >> 3;      // col half: 256 cols each
      const float* Wo = W_out + (size_t)j*DINNER*DMODEL;
      for (int i = tid; i < 4096; i += 256) {
        const int f = i*4;
        const int r = f >> 10, k = f & 1023;
        const int m = rt*16 + r;
        const int b = m >> 6, t1 = (m & 63) + 1;
        *(float4*)(lds + f) = *(const float4*)(ym + (size_t)(b*TT + t1)*DINNER + k);
      }
      __syncthreads();
      #pragma unroll
      for (int cc = 0; cc < 2; ++cc) {
        const int col0 = cth*256 + cc*128 + (tid & 63)*2;
        const int rq = tid >> 6;
        const float2* wp2 = (const float2*)(Wo + col0);   // stride 256 float2
        const float* ap = lds + rq*4*1024;
        float acc0[4] = {0,0,0,0}, acc1[4] = {0,0,0,0};
        for (int k = 0; k < 1024; k += 4) {
          const float2 w0 = wp2[(size_t)(k+0)*256];
          const float2 w1 = wp2[(size_t)(k+1)*256];
          const float2 w2 = wp2[(size_t)(k+2)*256];
          const float2 w3 = wp2[(size_t)(k+3)*256];
          #pragma unroll
          for (int r4 = 0; r4 < 4; ++r4) {
            const float4 a = *(const float4*)(ap + r4*1024 + k);
            acc0[r4] = fmaf(a.x, w0.x, acc0[r4]); acc1[r4] = fmaf(a.x, w0.y, acc1[r4]);
            acc0[r4] = fmaf(a.y, w1.x, acc0[r4]); acc1[r4] = fmaf(a.y, w1.y, acc1[r4]);
            acc0[r4] = fmaf(a.z, w2.x, acc0[r4]); acc1[r4] = fmaf(a.z, w2.y, acc1[r4]);
            acc0[r4] = fmaf(a.w, w3.x, acc0[r4]); acc1[r4] = fmaf(a.w, w3.y, acc1[r4]);
          }
        }
        #pragma unroll
        for (int r4 = 0; r4 < 4; ++r4) {
          const int m = rt*16 + rq*4 + r4;
          const int b = m >> 6, tm = m & 63;
          float* hp = h_ + (size_t)(b*SEQL + c*BLKSZ + tm)*DMODEL + col0;
          const float2 hv = *(const float2*)hp;
          *(float2*)hp = make_float2(hv.x + acc0[r4], hv.y + acc1[r4]);
          if (tm == 63) {
            *(float2*)(st_ + ((size_t)j*BATCH + b)*DMODEL + col0) = make_float2(acc0[r4], acc1[r4]);
            if (j == NLAYER-1)
              *(float2*)(memb + ((size_t)b*NCHUNK + c)*DMODEL + col0) = make_float2(acc0[r4], acc1[r4]);
          }
        }
      }
    }
    grid.sync();
  }
}

// ============================================================================
// Post kernels.
// ============================================================================
__global__ void __launch_bounds__(256,1)
transpose_k(const float* __restrict__ wq, const float* __restrict__ wk,
            const float* __restrict__ wvm, const float* __restrict__ wo,
            float* __restrict__ ws)
{
  float* wt = ws + OFF_WT;
  const float* srcs[4] = { wq, wk, wvm, wo };
  const int which = blockIdx.x >> 10;
  const int idx = ((blockIdx.x & 1023) << 8) + threadIdx.x;
  const int o = idx >> 9, m = idx & 511;
  wt[(size_t)which*262144 + (size_t)m*512 + o] = srcs[which][(size_t)o*512 + m];
}

__global__ void __launch_bounds__(256,1)
qkv_k(const float* __restrict__ bq, const float* __restrict__ bk, const float* __restrict__ bv,
      float* __restrict__ ws)
{
  __shared__ __align__(16) float lds[8192];
  const float* wt = ws + OFF_WT;
  const int wg = blockIdx.x, tid = threadIdx.x;
  const int rtg = wg >> 2, ct = wg & 3;
  const float* A; const float* Bm; const float* bias; float* out; int m0;
  if (rtg < 256)      { A = ws+OFF_H;   Bm = wt;          bias = bq; out = ws+OFF_Q; m0 = rtg*16; }
  else if (rtg < 260) { A = ws+OFF_MEM; Bm = wt + 262144; bias = bk; out = ws+OFF_K; m0 = (rtg-256)*16; }
  else                { A = ws+OFF_MEM; Bm = wt + 524288; bias = bv; out = ws+OFF_V; m0 = (rtg-260)*16; }
  for (int i = tid; i < 2048; i += 256) {
    const int f = i*4;
    *(float4*)(lds+f) = *(const float4*)(A + (size_t)(m0 + (f>>9))*512 + (f & 511));
  }
  __syncthreads();
  const int col0 = ct*128 + (tid & 63)*2;
  const int rq = tid >> 6;
  const float2* wp2 = (const float2*)(Bm + col0);    // stride 256 float2
  const float* ap = lds + rq*2048;
  float acc0[4] = {0,0,0,0}, acc1[4] = {0,0,0,0};
  for (int k = 0; k < 512; k += 4) {
    const float2 w0 = wp2[(size_t)(k+0)*256];
    const float2 w1 = wp2[(size_t)(k+1)*256];
    const float2 w2 = wp2[(size_t)(k+2)*256];
    const float2 w3 = wp2[(size_t)(k+3)*256];
    #pragma unroll
    for (int r4 = 0; r4 < 4; ++r4) {
      const float4 a = *(const float4*)(ap + r4*512 + k);
      acc0[r4] = fmaf(a.x, w0.x, acc0[r4]); acc1[r4] = fmaf(a.x, w0.y, acc1[r4]);
      acc0[r4] = fmaf(a.y, w1.x, acc0[r4]); acc1[r4] = fmaf(a.y, w1.y, acc1[r4]);
      acc0[r4] = fmaf(a.z, w2.x, acc0[r4]); acc1[r4] = fmaf(a.z, w2.y, acc1[r4]);
      acc0[r4] = fmaf(a.w, w3.x, acc0[r4]); acc1[r4] = fmaf(a.w, w3.y, acc1[r4]);
    }
  }
  const float bb0 = bias[col0], bb1 = bias[col0+1];
  #pragma unroll
  for (int r4 = 0; r4 < 4; ++r4)
    *(float2*)(out + (size_t)(m0 + rq*4 + r4)*512 + col0) = make_float2(acc0[r4]+bb0, acc1[r4]+bb1);
}

__global__ void __launch_bounds__(256,1)
attn_k(float* __restrict__ ws)
{
  const float* q  = ws + OFF_Q;
  const float* kk = ws + OFF_K;
  const float* vvv = ws + OFF_V;
  float* ao = ws + OFF_AO;
  const int gw = (blockIdx.x*256 + threadIdx.x) >> 6;   // wave id
  const int ln = threadIdx.x & 63;
  const int l = gw & (SEQL-1);
  const int bh = gw >> 11;
  const int b = bh >> 2, hh = bh & 3;
  const int tb = l >> 6;
  float* aop = ao + (size_t)(b*SEQL + l)*512 + hh*128;
  if (tb == 0) { *(float2*)(aop + ln*2) = make_float2(0.f, 0.f); return; }
  float sc = -1e30f;
  if (ln < tb) {
    const float* qp = q + (size_t)(b*SEQL+l)*512 + hh*128;
    const float* kp = kk + (size_t)(b*NCHUNK+ln)*512 + hh*128;
    float s = 0.f;
    for (int dd = 0; dd < 128; dd += 4) {
      const float4 qq = *(const float4*)(qp+dd);
      const float4 kv = *(const float4*)(kp+dd);
      s += qq.x*kv.x + qq.y*kv.y + qq.z*kv.z + qq.w*kv.w;
    }
    sc = s * 0.08838834764831845f;   // 1/sqrt(128)
  }
  float mx = sc;
  #pragma unroll
  for (int off = 32; off > 0; off >>= 1) mx = fmaxf(mx, __shfl_xor(mx, off));
  const float w = (ln < tb) ? __expf(sc - mx) : 0.f;
  float sm = w;
  #pragma unroll
  for (int off = 32; off > 0; off >>= 1) sm += __shfl_xor(sm, off);
  const float inv = 1.f / sm;
  float a0 = 0.f, a1 = 0.f;
  const int d0 = ln*2;
  for (int mm = 0; mm < tb; ++mm) {
    const float am = __shfl(w, mm) * inv;
    const float2 vp = *(const float2*)(vvv + (size_t)(b*NCHUNK+mm)*512 + hh*128 + d0);
    a0 = fmaf(am, vp.x, a0);
    a1 = fmaf(am, vp.y, a1);
  }
  *(float2*)(aop + d0) = make_float2(a0, a1);
}

__global__ void __launch_bounds__(256,1)
outproj_k(const float* __restrict__ bo, float* __restrict__ ws)
{
  __shared__ __align__(16) float lds[8192];
  float* ao  = ws + OFF_AO;            // in: attention out; out: hres (in place)
  const float* woT = ws + OFF_WT + 786432;
  const float* h_ = ws + OFF_H;
  const int wg = blockIdx.x, tid = threadIdx.x;
  const int rtg = wg >> 2, ct = wg & 3;
  const int m0 = rtg*16;
  for (int i = tid; i < 2048; i += 256) {
    const int f = i*4;
    *(float4*)(lds+f) = *(const float4*)(ao + (size_t)(m0 + (f>>9))*512 + (f & 511));
  }
  __syncthreads();
  const int col0 = ct*128 + (tid & 63)*2;
  const int rq = tid >> 6;
  const float2* wp2 = (const float2*)(woT + col0);
  const float* ap = lds + rq*2048;
  float acc0[4] = {0,0,0,0}, acc1[4] = {0,0,0,0};
  for (int k = 0; k < 512; k += 4) {
    const float2 w0 = wp2[(size_t)(k+0)*256];
    const float2 w1 = wp2[(size_t)(k+1)*256];
    const float2 w2 = wp2[(size_t)(k+2)*256];
    const float2 w3 = wp2[(size_t)(k+3)*256];
    #pragma unroll
    for (int r4 = 0; r4 < 4; ++r4) {
      const float4 a = *(const float4*)(ap + r4*512 + k);
      acc0[r4] = fmaf(a.x, w0.x, acc0[r4]); acc1[r4] = fmaf(a.x, w0.y, acc1[r4]);
      acc0[r4] = fmaf(a.y, w1.x, acc0[r4]); acc1[r4] = fmaf(a.y, w1.y, acc1[r4]);
      acc0[r4] = fmaf(a.z, w2.x, acc0[r4]); acc1[r4] = fmaf(a.z, w2.y, acc1[r4]);
      acc0[r4] = fmaf(a.w, w3.x, acc0[r4]); acc1[r4] = fmaf(a.w, w3.y, acc1[r4]);
    }
  }
  const float bb0 = bo[col0], bb1 = bo[col0+1];
  #pragma unroll
  for (int r4 = 0; r4 < 4; ++r4) {
    const int m = m0 + rq*4 + r4;
    const float hp = ((m & (SEQL-1)) >= BLKSZ) ? 1.f : 0.f;
    const float2 hv = *(const float2*)(h_ + (size_t)m*512 + col0);
    *(float2*)(ao + (size_t)m*512 + col0) =
        make_float2(hv.x + (acc0[r4]+bb0)*hp, hv.y + (acc1[r4]+bb1)*hp);
  }
}

__global__ void __launch_bounds__(256,1)
lnhead_k(const float* __restrict__ lnw, const float* __restrict__ lnb,
         const float* __restrict__ head_w, float* __restrict__ ws, float* __restrict__ out)
{
  __shared__ __align__(16) float lds[8192];
  const float* hres = ws + OFF_AO;
  const int wg = blockIdx.x, tid = threadIdx.x;
  const int wv = tid >> 6, ln = tid & 63;
  const int rtg = wg >> 2, ct = wg & 3;
  const int m0 = rtg*16;
  for (int r = wv; r < 16; r += 4) {
    const float* src = hres + (size_t)(m0+r)*512 + ln*8;
    const float4 v0 = *(const float4*)src;
    const float4 v1 = *(const float4*)(src+4);
    float s1 = v0.x+v0.y+v0.z+v0.w + v1.x+v1.y+v1.z+v1.w;
    float s2 = v0.x*v0.x+v0.y*v0.y+v0.z*v0.z+v0.w*v0.w
             + v1.x*v1.x+v1.y*v1.y+v1.z*v1.z+v1.w*v1.w;
    #pragma unroll
    for (int off = 32; off > 0; off >>= 1) { s1 += __shfl_xor(s1, off); s2 += __shfl_xor(s2, off); }
    const float mu = s1 * (1.f/512.f);
    const float var = fmaxf(s2 * (1.f/512.f) - mu*mu, 0.f);
    const float nf = rsqrtf(var + 1e-5f);
    const float o[8] = {v0.x,v0.y,v0.z,v0.w,v1.x,v1.y,v1.z,v1.w};
    #pragma unroll
    for (int x = 0; x < 8; ++x)
      lds[r*512 + ln*8 + x] = (o[x]-mu)*nf*lnw[ln*8+x] + lnb[ln*8+x];
  }
  __syncthreads();
  const int col0 = ct*128 + (tid & 63)*2;
  const int rq = tid >> 6;
  const float2* wp2 = (const float2*)(head_w + col0);
  const float* ap = lds + rq*2048;
  float acc0[4] = {0,0,0,0}, acc1[4] = {0,0,0,0};
  for (int k = 0; k < 512; k += 4) {
    const float2 w0 = wp2[(size_t)(k+0)*256];
    const float2 w1 = wp2[(size_t)(k+1)*256];
    const float2 w2 = wp2[(size_t)(k+2)*256];
    const float2 w3 = wp2[(size_t)(k+3)*256];
    #pragma unroll
    for (int r4 = 0; r4 < 4; ++r4) {
      const float4 a = *(const float4*)(ap + r4*512 + k);
      acc0[r4] = fmaf(a.x, w0.x, acc0[r4]); acc1[r4] = fmaf(a.x, w0.y, acc1[r4]);
      acc0[r4] = fmaf(a.y, w1.x, acc0[r4]); acc1[r4] = fmaf(a.y, w1.y, acc1[r4]);
      acc0[r4] = fmaf(a.z, w2.x, acc0[r4]); acc1[r4] = fmaf(a.z, w2.y, acc1[r4]);
      acc0[r4] = fmaf(a.w, w3.x, acc0[r4]); acc1[r4] = fmaf(a.w, w3.y, acc1[r4]);
    }
  }
  #pragma unroll
  for (int r4 = 0; r4 < 4; ++r4) {
    const size_t oi = (size_t)(m0 + rq*4 + r4)*512 + col0;
    *(float2*)(out + oi) = make_float2(acc0[r4], acc1[r4]);
  }
}

extern "C" void kernel_launch(void* const* d_in, const int* in_sizes, int n_in,
                              void* d_out, int out_size, void* d_ws, size_t ws_size,
                              hipStream_t stream)
{
  const int*   tokens     = (const int*)d_in[0];
  const float* embed      = (const float*)d_in[1];
  const float* rms_w      = (const float*)d_in[2];
  const float* W_in       = (const float*)d_in[3];
  const float* conv_w     = (const float*)d_in[4];
  const float* conv_b     = (const float*)d_in[5];
  const float* x_proj     = (const float*)d_in[6];
  const float* dt_w       = (const float*)d_in[7];
  const float* dt_b       = (const float*)d_in[8];
  const float* A_log      = (const float*)d_in[9];
  const float* D_skip     = (const float*)d_in[10];
  const float* W_out      = (const float*)d_in[11];
  const float* init_state = (const float*)d_in[12];
  const float* Wq         = (const float*)d_in[13];
  const float* Wk         = (const float*)d_in[14];
  const float* Wv         = (const float*)d_in[15];
  const float* bq         = (const float*)d_in[16];
  const float* bk         = (const float*)d_in[17];
  const float* bv         = (const float*)d_in[18];
  const float* Wo_attn    = (const float*)d_in[19];
  const float* bo         = (const float*)d_in[20];
  const float* ln_w       = (const float*)d_in[21];
  const float* ln_b       = (const float*)d_in[22];
  const float* head_w     = (const float*)d_in[23];
  float* ws = (float*)d_ws;
  float* out = (float*)d_out;

  hipLaunchKernelGGL(transpose_k, dim3(4096), dim3(256), 0, stream, Wq, Wk, Wv, Wo_attn, ws);

  void* args[] = { (void*)&tokens, (void*)&embed, (void*)&rms_w, (void*)&W_in,
                   (void*)&conv_w, (void*)&conv_b, (void*)&x_proj, (void*)&dt_w,
                   (void*)&dt_b, (void*)&A_log, (void*)&D_skip, (void*)&W_out,
                   (void*)&init_state, (void*)&ws };
  hipLaunchCooperativeKernel(reinterpret_cast<const void*>(&mamba_coop),
                             dim3(240), dim3(256), args, 0, stream);

  hipLaunchKernelGGL(qkv_k, dim3(1056), dim3(256), 0, stream, bq, bk, bv, ws);
  hipLaunchKernelGGL(attn_k, dim3(4096), dim3(256), 0, stream, ws);
  hipLaunchKernelGGL(outproj_k, dim3(1024), dim3(256), 0, stream, bo, ws);
  hipLaunchKernelGGL(lnhead_k, dim3(1024), dim3(256), 0, stream, ln_w, ln_b, head_w, ws, out);
}

// Round 4
// 15941.705 us; speedup vs baseline: 1.6041x; 1.6041x over previous
//
#include <hip/hip_runtime.h>
#include <hip/hip_cooperative_groups.h>

namespace cg = cooperative_groups;

typedef unsigned short u16;
typedef unsigned int u32;
typedef __attribute__((ext_vector_type(8))) short bf16x8;
typedef __attribute__((ext_vector_type(4))) float f32x4;

constexpr int BATCH = 2, SEQL = 2048, DMODEL = 512, DINNER = 1024;
constexpr int NLAYER = 15, BLKSZ = 64, NCHUNK = 32, TT = 65;

// ---- workspace layout (float units). Total 23,188,480 f = 92.8 MB ----
constexpr size_t OFF_H   = 0;                      // [B*L][512] f32      2,097,152
constexpr size_t OFF_ST  = 2097152;                // [15][2][512] f32       15,360
constexpr size_t OFF_MEM = 2112512;                // [2][32][512] f32       32,768
constexpr size_t OFF_XZ  = 2145280;                // 15x[130][2048] f32  3,993,600
constexpr size_t OFF_XC  = 6138880;                // 15x[130][1024] f32  1,996,800
constexpr size_t OFF_ANB = 8135680;                // 15x[144][512] bf16    552,960 f
constexpr size_t OFF_XCB = 8688640;                // 15x[160][1024] bf16 1,228,800 f
constexpr size_t OFF_YMB = 9917440;                // 15x[128][1024] bf16   983,040 f
constexpr size_t OFF_WIT = 10900480;               // 15x[2048][512] bf16 7,864,320 f
constexpr size_t OFF_WOT = 18764800;               // 15x[512][1024] bf16 3,932,160 f
constexpr size_t OFF_XPT = 22696960;               // 15x[64][1024] bf16    491,520 f
// attention region aliases coop scratch [OFF_XZ, OFF_ANB):
constexpr size_t OFF_Q   = 2145280;
constexpr size_t OFF_K   = 4242432;
constexpr size_t OFF_V   = 4275200;
constexpr size_t OFF_AO  = 4307968;                // ao doubles as hres
constexpr size_t OFF_WTA = 6405120;                // 4 x 262144 f32 attn W^T

__device__ __forceinline__ u16 f2b(float f) {
  u32 u = __builtin_bit_cast(u32, f);
  u = (u + 0x7fffu + ((u >> 16) & 1u)) >> 16;
  return (u16)u;
}
__device__ __forceinline__ u32 pk2(float a, float b) {
  return (u32)f2b(a) | ((u32)f2b(b) << 16);
}

// ============================================================================
// Weight prep: f32 [R][C] row-major -> bf16 [C][R] (per-matrix), tiled 64x64.
// ============================================================================
__global__ void __launch_bounds__(256,2)
wtrans_k(const float* __restrict__ src, u16* __restrict__ dst,
         int R, int C, int tiles_rc, int tc)
{
  __shared__ float tile[64*65];
  const int mat = blockIdx.x / tiles_rc;
  const int rem = blockIdx.x % tiles_rc;
  const int r0 = (rem / tc) * 64, c0 = (rem % tc) * 64;
  const float* s = src + (size_t)mat * R * C;
  u16* d = dst + (size_t)mat * C * R;
  for (int i = threadIdx.x; i < 4096; i += 256) {
    const int r = i >> 6, cc = i & 63;
    tile[r*65 + cc] = s[(size_t)(r0 + r)*C + c0 + cc];
  }
  __syncthreads();
  for (int i = threadIdx.x; i < 4096; i += 256) {
    const int ci = i >> 6, rr = i & 63;
    d[(size_t)(c0 + ci)*R + r0 + rr] = f2b(tile[rr*65 + ci]);
  }
}

// ============================================================================
// Cooperative kernel: 2D wavefront over (chunk, layer); MFMA GEMMs.
// ============================================================================
__global__ void __launch_bounds__(256, 2)
mamba_coop(const int* __restrict__ tokens, const float* __restrict__ embed,
           const float* __restrict__ rms_w, const float* __restrict__ conv_w,
           const float* __restrict__ conv_b, const float* __restrict__ dt_w,
           const float* __restrict__ dt_b, const float* __restrict__ A_log,
           const float* __restrict__ D_skip, const float* __restrict__ init_state,
           float* __restrict__ ws)
{
  cg::grid_group grid = cg::this_grid();
  __shared__ __align__(16) float xd_lds[80*64];   // 20 KB
  float* h_  = ws + OFF_H;
  float* st_ = ws + OFF_ST;
  float* memb = ws + OFF_MEM;
  const int NWG = gridDim.x;
  const int wg = blockIdx.x, tid = threadIdx.x;
  const int wv = tid >> 6, ln = tid & 63;
  const int lr = ln & 15, lq = ln >> 4;

  // ---------- embedding gather + state init ----------
  {
    const int gtid = wg*256 + tid;
    const int gstr = NWG*256;
    for (int g = gtid; g < BATCH*SEQL*(DMODEL/8); g += gstr) {
      const int bl = g >> 6;
      const int m0 = (g & 63) << 3;
      const int tok = tokens[bl];
      const float* ep = embed + (size_t)tok*DMODEL + m0;
      float* hp = h_ + (size_t)bl*DMODEL + m0;
      *(float4*)hp     = *(const float4*)ep;
      *(float4*)(hp+4) = *(const float4*)(ep+4);
    }
    for (int i = gtid; i < NLAYER*BATCH*DMODEL; i += gstr) {
      const int m = i & (DMODEL-1);
      const int j = i / (BATCH*DMODEL);
      st_[i] = init_state[j*DMODEL + m];
    }
  }
  grid.sync();

  for (int diag = 0; diag < NCHUNK + NLAYER - 1; ++diag) {
    const int c_lo = (diag - (NLAYER-1)) > 0 ? (diag - (NLAYER-1)) : 0;
    const int c_hi = diag < (NCHUNK-1) ? diag : (NCHUNK-1);
    const int nst = c_hi - c_lo + 1;
    const int sidx = wg % nst;
    const int swg  = wg / nst;
    const int nwg  = (NWG - 1 - sidx)/nst + 1;
    const int c = c_lo + sidx;
    const int j = diag - c;
    float* xz  = ws + OFF_XZ + (size_t)j*266240;
    float* xcf = ws + OFF_XC + (size_t)j*133120;
    u16* anb = (u16*)(ws + OFF_ANB) + (size_t)j*73728;
    u16* xcb = (u16*)(ws + OFF_XCB) + (size_t)j*163840;
    u16* ymb = (u16*)(ws + OFF_YMB) + (size_t)j*131072;
    const u16* WiT = (const u16*)(ws + OFF_WIT) + (size_t)j*1048576;
    const u16* WoT = (const u16*)(ws + OFF_WOT) + (size_t)j*524288;
    const u16* XpT = (const u16*)(ws + OFF_XPT) + (size_t)j*65536;
    const float* rw = rms_w + (size_t)j*DMODEL;

    // -------- PA: anb = bf16([state; rmsnorm(co)]), rows padded to 144 ------
    {
      const int nwaves = nwg*4;
      for (int m = swg*4 + wv; m < 144; m += nwaves) {
        const int k0 = ln*8;
        uint4 pk;
        if (m < 130) {
          const int b = m/TT, t = m - b*TT;
          float v[8];
          if (t == 0) {
            const float* sp = st_ + ((size_t)j*BATCH + b)*DMODEL + k0;
            #pragma unroll
            for (int x = 0; x < 8; ++x) v[x] = sp[x];
          } else {
            const float* hp = h_ + (size_t)(b*SEQL + c*BLKSZ + t-1)*DMODEL + k0;
            const float4 v0 = *(const float4*)hp;
            const float4 v1 = *(const float4*)(hp+4);
            float ss = v0.x*v0.x + v0.y*v0.y + v0.z*v0.z + v0.w*v0.w
                     + v1.x*v1.x + v1.y*v1.y + v1.z*v1.z + v1.w*v1.w;
            #pragma unroll
            for (int off = 32; off > 0; off >>= 1) ss += __shfl_xor(ss, off);
            const float rs = rsqrtf(ss * (1.f/512.f) + 1e-6f);
            const float o[8] = {v0.x,v0.y,v0.z,v0.w,v1.x,v1.y,v1.z,v1.w};
            #pragma unroll
            for (int x = 0; x < 8; ++x) v[x] = o[x] * rs * rw[k0 + x];
          }
          pk = make_uint4(pk2(v[0],v[1]), pk2(v[2],v[3]), pk2(v[4],v[5]), pk2(v[6],v[7]));
        } else {
          pk = make_uint4(0,0,0,0);
        }
        *(uint4*)(anb + (size_t)m*512 + k0) = pk;
      }
    }
    grid.sync();

    // -------- PB: xz = anb @ W_inT (130x2048, K=512) via MFMA; + fused conv -
    {
      const float* cvb = conv_b + (size_t)j*DINNER;
      const float* cww = conv_w + (size_t)j*DINNER*4;
      for (int nb = swg; nb < 32; nb += nwg) {
        const int n_base = nb*64;
        f32x4 acc[3][4] = {};
        for (int kk = 0; kk < 16; ++kk) {
          const int k0 = kk*32 + lq*8;
          bf16x8 bf[4];
          #pragma unroll
          for (int nt = 0; nt < 4; ++nt)
            bf[nt] = *(const bf16x8*)(WiT + (size_t)(n_base + nt*16 + lr)*512 + k0);
          #pragma unroll
          for (int i = 0; i < 3; ++i) {
            if (i == 2 && wv != 0) continue;
            const int mt = wv + 4*i;
            const bf16x8 af = *(const bf16x8*)(anb + (size_t)(mt*16 + lr)*512 + k0);
            #pragma unroll
            for (int nt = 0; nt < 4; ++nt)
              acc[i][nt] = __builtin_amdgcn_mfma_f32_16x16x32_bf16(af, bf[nt], acc[i][nt], 0, 0, 0);
          }
        }
        #pragma unroll
        for (int i = 0; i < 3; ++i) {
          if (i == 2 && wv != 0) continue;
          const int mt = wv + 4*i;
          #pragma unroll
          for (int nt = 0; nt < 4; ++nt)
            #pragma unroll
            for (int r = 0; r < 4; ++r) {
              const int m = mt*16 + lq*4 + r;
              if (m < 130)
                xz[(size_t)m*2048 + n_base + nt*16 + lr] = acc[i][nt][r];
            }
        }
        if (nb < 16) {      // conv+silu epilogue for this WG's own 64 x-columns
          __syncthreads();
          for (int e = tid; e < 64*160; e += 256) {
            const int d = n_base + (e & 63);
            const int row2 = e >> 6;
            const int b = row2 / 80, t = row2 - b*80;
            if (t < TT) {
              const int m = b*TT + t;
              float a = cvb[d];
              #pragma unroll
              for (int q = 0; q < 4; ++q) {
                const int tt = t - 3 + q;
                if (tt >= 0) a = fmaf(xz[(size_t)(b*TT+tt)*2048 + d], cww[d*4+q], a);
              }
              const float sv = a / (1.f + __expf(-a));
              xcf[(size_t)m*1024 + d] = sv;
              xcb[(size_t)row2*1024 + d] = f2b(sv);
            } else {
              xcb[(size_t)row2*1024 + d] = 0;
            }
          }
        }
      }
    }
    grid.sync();

    // -------- PD: xd = xcb @ x_projT (65x64,K=1024) MFMA -> LDS; then scan --
    if (swg < 8) {
      const int p = swg, b = p >> 2;
      const u16* xa = xcb + (size_t)b*80*1024;
      for (int mt = 0; mt < 5; ++mt) {
        f32x4 acc = {};
        for (int kk = 0; kk < 32; ++kk) {
          const int k0 = kk*32 + lq*8;
          const bf16x8 af = *(const bf16x8*)(xa + (size_t)(mt*16 + lr)*1024 + k0);
          const bf16x8 bf = *(const bf16x8*)(XpT + (size_t)(wv*16 + lr)*1024 + k0);
          acc = __builtin_amdgcn_mfma_f32_16x16x32_bf16(af, bf, acc, 0, 0, 0);
        }
        #pragma unroll
        for (int r = 0; r < 4; ++r)
          xd_lds[(mt*16 + lq*4 + r)*64 + wv*16 + lr] = acc[r];
      }
      __syncthreads();
      // selective scan, one thread per (b,d)
      const int d = (p & 3)*256 + tid;
      float dtwr[32];
      const float* dwp = dt_w + (size_t)j*32*DINNER + d;
      #pragma unroll
      for (int r = 0; r < 32; ++r) dtwr[r] = dwp[(size_t)r*DINNER];
      float Ai[16], s[16];
      const float* alp = A_log + (size_t)j*DINNER*16 + (size_t)d*16;
      #pragma unroll
      for (int i = 0; i < 16; ++i) { Ai[i] = -__expf(alp[i]); s[i] = 0.f; }
      const float dtbv = dt_b[(size_t)j*DINNER + d];
      const float Dv   = D_skip[(size_t)j*DINNER + d];
      for (int t = 0; t < TT; ++t) {
        const float4* row = (const float4*)(xd_lds + t*64);
        float dl = dtbv;
        #pragma unroll
        for (int r = 0; r < 8; ++r) {
          const float4 x = row[r];
          dl = fmaf(x.x, dtwr[4*r+0], dl);
          dl = fmaf(x.y, dtwr[4*r+1], dl);
          dl = fmaf(x.z, dtwr[4*r+2], dl);
          dl = fmaf(x.w, dtwr[4*r+3], dl);
        }
        const float e = __expf(dl);
        const float dtv = (dl > 15.f) ? dl : log1pf(e);
        const float xcv = xcf[(size_t)(b*TT+t)*1024 + d];
        const float u = dtv * xcv;
        float yv = 0.f;
        #pragma unroll
        for (int i = 0; i < 4; ++i) {
          const float4 Bv = row[8+i];
          const float4 Cv = row[12+i];
          float P;
          P = __expf(dtv*Ai[4*i+0]); s[4*i+0] = fmaf(s[4*i+0], P, u*Bv.x); yv = fmaf(s[4*i+0], Cv.x, yv);
          P = __expf(dtv*Ai[4*i+1]); s[4*i+1] = fmaf(s[4*i+1], P, u*Bv.y); yv = fmaf(s[4*i+1], Cv.y, yv);
          P = __expf(dtv*Ai[4*i+2]); s[4*i+2] = fmaf(s[4*i+2], P, u*Bv.z); yv = fmaf(s[4*i+2], Cv.z, yv);
          P = __expf(dtv*Ai[4*i+3]); s[4*i+3] = fmaf(s[4*i+3], P, u*Bv.w); yv = fmaf(s[4*i+3], Cv.w, yv);
        }
        const float zv = xz[(size_t)(b*TT+t)*2048 + 1024 + d];
        const float sz = zv / (1.f + __expf(-zv));
        if (t >= 1)
          ymb[(size_t)(b*64 + t-1)*1024 + d] = f2b((yv + Dv*xcv) * sz);
      }
    }
    grid.sync();

    // -------- PE: lo = ymb @ W_outT (128x512,K=1024) MFMA; h+=, state/mem ---
    {
      for (int nt0 = swg; nt0 < 32; nt0 += nwg) {
        f32x4 acc[2] = {};
        for (int kk = 0; kk < 32; ++kk) {
          const int k0 = kk*32 + lq*8;
          const bf16x8 bf = *(const bf16x8*)(WoT + (size_t)(nt0*16 + lr)*1024 + k0);
          #pragma unroll
          for (int i = 0; i < 2; ++i) {
            const int mt = wv*2 + i;
            const bf16x8 af = *(const bf16x8*)(ymb + (size_t)(mt*16 + lr)*1024 + k0);
            acc[i] = __builtin_amdgcn_mfma_f32_16x16x32_bf16(af, bf, acc[i], 0, 0, 0);
          }
        }
        const int col = nt0*16 + lr;
        #pragma unroll
        for (int i = 0; i < 2; ++i) {
          const int mt = wv*2 + i;
          #pragma unroll
          for (int r = 0; r < 4; ++r) {
            const int m = mt*16 + lq*4 + r;
            const int b = m >> 6, tm = m & 63;
            const float v = acc[i][r];
            float* hp = h_ + (size_t)(b*SEQL + c*BLKSZ + tm)*DMODEL + col;
            *hp += v;
            if (tm == 63) {
              st_[((size_t)j*BATCH + b)*DMODEL + col] = v;
              if (j == NLAYER-1)
                memb[((size_t)b*NCHUNK + c)*DMODEL + col] = v;
            }
          }
        }
      }
    }
    grid.sync();
  }
}

// ============================================================================
// Post kernels (f32, as validated in round 3; offsets updated).
// ============================================================================
__global__ void __launch_bounds__(256,1)
transpose_k(const float* __restrict__ wq, const float* __restrict__ wk,
            const float* __restrict__ wvm, const float* __restrict__ wo,
            float* __restrict__ ws)
{
  float* wt = ws + OFF_WTA;
  const float* srcs[4] = { wq, wk, wvm, wo };
  const int which = blockIdx.x >> 10;
  const int idx = ((blockIdx.x & 1023) << 8) + threadIdx.x;
  const int o = idx >> 9, m = idx & 511;
  wt[(size_t)which*262144 + (size_t)m*512 + o] = srcs[which][(size_t)o*512 + m];
}

__global__ void __launch_bounds__(256,1)
qkv_k(const float* __restrict__ bq, const float* __restrict__ bk, const float* __restrict__ bv,
      float* __restrict__ ws)
{
  __shared__ __align__(16) float lds[8192];
  const float* wt = ws + OFF_WTA;
  const int wg = blockIdx.x, tid = threadIdx.x;
  const int rtg = wg >> 2, ct = wg & 3;
  const float* A; const float* Bm; const float* bias; float* out; int m0;
  if (rtg < 256)      { A = ws+OFF_H;   Bm = wt;          bias = bq; out = ws+OFF_Q; m0 = rtg*16; }
  else if (rtg < 260) { A = ws+OFF_MEM; Bm = wt + 262144; bias = bk; out = ws+OFF_K; m0 = (rtg-256)*16; }
  else                { A = ws+OFF_MEM; Bm = wt + 524288; bias = bv; out = ws+OFF_V; m0 = (rtg-260)*16; }
  for (int i = tid; i < 2048; i += 256) {
    const int f = i*4;
    *(float4*)(lds+f) = *(const float4*)(A + (size_t)(m0 + (f>>9))*512 + (f & 511));
  }
  __syncthreads();
  const int col0 = ct*128 + (tid & 63)*2;
  const int rq = tid >> 6;
  const float2* wp2 = (const float2*)(Bm + col0);
  const float* ap = lds + rq*2048;
  float acc0[4] = {0,0,0,0}, acc1[4] = {0,0,0,0};
  for (int k = 0; k < 512; k += 4) {
    const float2 w0 = wp2[(size_t)(k+0)*256];
    const float2 w1 = wp2[(size_t)(k+1)*256];
    const float2 w2 = wp2[(size_t)(k+2)*256];
    const float2 w3 = wp2[(size_t)(k+3)*256];
    #pragma unroll
    for (int r4 = 0; r4 < 4; ++r4) {
      const float4 a = *(const float4*)(ap + r4*512 + k);
      acc0[r4] = fmaf(a.x, w0.x, acc0[r4]); acc1[r4] = fmaf(a.x, w0.y, acc1[r4]);
      acc0[r4] = fmaf(a.y, w1.x, acc0[r4]); acc1[r4] = fmaf(a.y, w1.y, acc1[r4]);
      acc0[r4] = fmaf(a.z, w2.x, acc0[r4]); acc1[r4] = fmaf(a.z, w2.y, acc1[r4]);
      acc0[r4] = fmaf(a.w, w3.x, acc0[r4]); acc1[r4] = fmaf(a.w, w3.y, acc1[r4]);
    }
  }
  const float bb0 = bias[col0], bb1 = bias[col0+1];
  #pragma unroll
  for (int r4 = 0; r4 < 4; ++r4)
    *(float2*)(out + (size_t)(m0 + rq*4 + r4)*512 + col0) = make_float2(acc0[r4]+bb0, acc1[r4]+bb1);
}

__global__ void __launch_bounds__(256,1)
attn_k(float* __restrict__ ws)
{
  const float* q  = ws + OFF_Q;
  const float* kk = ws + OFF_K;
  const float* vvv = ws + OFF_V;
  float* ao = ws + OFF_AO;
  const int gw = (blockIdx.x*256 + threadIdx.x) >> 6;
  const int ln = threadIdx.x & 63;
  const int l = gw & (SEQL-1);
  const int bh = gw >> 11;
  const int b = bh >> 2, hh = bh & 3;
  const int tb = l >> 6;
  float* aop = ao + (size_t)(b*SEQL + l)*512 + hh*128;
  if (tb == 0) { *(float2*)(aop + ln*2) = make_float2(0.f, 0.f); return; }
  float sc = -1e30f;
  if (ln < tb) {
    const float* qp = q + (size_t)(b*SEQL+l)*512 + hh*128;
    const float* kp = kk + (size_t)(b*NCHUNK+ln)*512 + hh*128;
    float s = 0.f;
    for (int dd = 0; dd < 128; dd += 4) {
      const float4 qq = *(const float4*)(qp+dd);
      const float4 kv = *(const float4*)(kp+dd);
      s += qq.x*kv.x + qq.y*kv.y + qq.z*kv.z + qq.w*kv.w;
    }
    sc = s * 0.08838834764831845f;
  }
  float mx = sc;
  #pragma unroll
  for (int off = 32; off > 0; off >>= 1) mx = fmaxf(mx, __shfl_xor(mx, off));
  const float w = (ln < tb) ? __expf(sc - mx) : 0.f;
  float sm = w;
  #pragma unroll
  for (int off = 32; off > 0; off >>= 1) sm += __shfl_xor(sm, off);
  const float inv = 1.f / sm;
  float a0 = 0.f, a1 = 0.f;
  const int d0 = ln*2;
  for (int mm = 0; mm < tb; ++mm) {
    const float am = __shfl(w, mm) * inv;
    const float2 vp = *(const float2*)(vvv + (size_t)(b*NCHUNK+mm)*512 + hh*128 + d0);
    a0 = fmaf(am, vp.x, a0);
    a1 = fmaf(am, vp.y, a1);
  }
  *(float2*)(aop + d0) = make_float2(a0, a1);
}

__global__ void __launch_bounds__(256,1)
outproj_k(const float* __restrict__ bo, float* __restrict__ ws)
{
  __shared__ __align__(16) float lds[8192];
  float* ao  = ws + OFF_AO;
  const float* woT = ws + OFF_WTA + 786432;
  const float* h_ = ws + OFF_H;
  const int wg = blockIdx.x, tid = threadIdx.x;
  const int rtg = wg >> 2, ct = wg & 3;
  const int m0 = rtg*16;
  for (int i = tid; i < 2048; i += 256) {
    const int f = i*4;
    *(float4*)(lds+f) = *(const float4*)(ao + (size_t)(m0 + (f>>9))*512 + (f & 511));
  }
  __syncthreads();
  const int col0 = ct*128 + (tid & 63)*2;
  const int rq = tid >> 6;
  const float2* wp2 = (const float2*)(woT + col0);
  const float* ap = lds + rq*2048;
  float acc0[4] = {0,0,0,0}, acc1[4] = {0,0,0,0};
  for (int k = 0; k < 512; k += 4) {
    const float2 w0 = wp2[(size_t)(k+0)*256];
    const float2 w1 = wp2[(size_t)(k+1)*256];
    const float2 w2 = wp2[(size_t)(k+2)*256];
    const float2 w3 = wp2[(size_t)(k+3)*256];
    #pragma unroll
    for (int r4 = 0; r4 < 4; ++r4) {
      const float4 a = *(const float4*)(ap + r4*512 + k);
      acc0[r4] = fmaf(a.x, w0.x, acc0[r4]); acc1[r4] = fmaf(a.x, w0.y, acc1[r4]);
      acc0[r4] = fmaf(a.y, w1.x, acc0[r4]); acc1[r4] = fmaf(a.y, w1.y, acc1[r4]);
      acc0[r4] = fmaf(a.z, w2.x, acc0[r4]); acc1[r4] = fmaf(a.z, w2.y, acc1[r4]);
      acc0[r4] = fmaf(a.w, w3.x, acc0[r4]); acc1[r4] = fmaf(a.w, w3.y, acc1[r4]);
    }
  }
  const float bb0 = bo[col0], bb1 = bo[col0+1];
  #pragma unroll
  for (int r4 = 0; r4 < 4; ++r4) {
    const int m = m0 + rq*4 + r4;
    const float hp = ((m & (SEQL-1)) >= BLKSZ) ? 1.f : 0.f;
    const float2 hv = *(const float2*)(h_ + (size_t)m*512 + col0);
    *(float2*)(ao + (size_t)m*512 + col0) =
        make_float2(hv.x + (acc0[r4]+bb0)*hp, hv.y + (acc1[r4]+bb1)*hp);
  }
}

__global__ void __launch_bounds__(256,1)
lnhead_k(const float* __restrict__ lnw, const float* __restrict__ lnb,
         const float* __restrict__ head_w, float* __restrict__ ws, float* __restrict__ out)
{
  __shared__ __align__(16) float lds[8192];
  const float* hres = ws + OFF_AO;
  const int wg = blockIdx.x, tid = threadIdx.x;
  const int wv = tid >> 6, ln = tid & 63;
  const int rtg = wg >> 2, ct = wg & 3;
  const int m0 = rtg*16;
  for (int r = wv; r < 16; r += 4) {
    const float* src = hres + (size_t)(m0+r)*512 + ln*8;
    const float4 v0 = *(const float4*)src;
    const float4 v1 = *(const float4*)(src+4);
    float s1 = v0.x+v0.y+v0.z+v0.w + v1.x+v1.y+v1.z+v1.w;
    float s2 = v0.x*v0.x+v0.y*v0.y+v0.z*v0.z+v0.w*v0.w
             + v1.x*v1.x+v1.y*v1.y+v1.z*v1.z+v1.w*v1.w;
    #pragma unroll
    for (int off = 32; off > 0; off >>= 1) { s1 += __shfl_xor(s1, off); s2 += __shfl_xor(s2, off); }
    const float mu = s1 * (1.f/512.f);
    const float var = fmaxf(s2 * (1.f/512.f) - mu*mu, 0.f);
    const float nf = rsqrtf(var + 1e-5f);
    const float o[8] = {v0.x,v0.y,v0.z,v0.w,v1.x,v1.y,v1.z,v1.w};
    #pragma unroll
    for (int x = 0; x < 8; ++x)
      lds[r*512 + ln*8 + x] = (o[x]-mu)*nf*lnw[ln*8+x] + lnb[ln*8+x];
  }
  __syncthreads();
  const int col0 = ct*128 + (tid & 63)*2;
  const int rq = tid >> 6;
  const float2* wp2 = (const float2*)(head_w + col0);
  const float* ap = lds + rq*2048;
  float acc0[4] = {0,0,0,0}, acc1[4] = {0,0,0,0};
  for (int k = 0; k < 512; k += 4) {
    const float2 w0 = wp2[(size_t)(k+0)*256];
    const float2 w1 = wp2[(size_t)(k+1)*256];
    const float2 w2 = wp2[(size_t)(k+2)*256];
    const float2 w3 = wp2[(size_t)(k+3)*256];
    #pragma unroll
    for (int r4 = 0; r4 < 4; ++r4) {
      const float4 a = *(const float4*)(ap + r4*512 + k);
      acc0[r4] = fmaf(a.x, w0.x, acc0[r4]); acc1[r4] = fmaf(a.x, w0.y, acc1[r4]);
      acc0[r4] = fmaf(a.y, w1.x, acc0[r4]); acc1[r4] = fmaf(a.y, w1.y, acc1[r4]);
      acc0[r4] = fmaf(a.z, w2.x, acc0[r4]); acc1[r4] = fmaf(a.z, w2.y, acc1[r4]);
      acc0[r4] = fmaf(a.w, w3.x, acc0[r4]); acc1[r4] = fmaf(a.w, w3.y, acc1[r4]);
    }
  }
  #pragma unroll
  for (int r4 = 0; r4 < 4; ++r4) {
    const size_t oi = (size_t)(m0 + rq*4 + r4)*512 + col0;
    *(float2*)(out + oi) = make_float2(acc0[r4], acc1[r4]);
  }
}

extern "C" void kernel_launch(void* const* d_in, const int* in_sizes, int n_in,
                              void* d_out, int out_size, void* d_ws, size_t ws_size,
                              hipStream_t stream)
{
  const int*   tokens     = (const int*)d_in[0];
  const float* embed      = (const float*)d_in[1];
  const float* rms_w      = (const float*)d_in[2];
  const float* W_in       = (const float*)d_in[3];
  const float* conv_w     = (const float*)d_in[4];
  const float* conv_b     = (const float*)d_in[5];
  const float* x_proj     = (const float*)d_in[6];
  const float* dt_w       = (const float*)d_in[7];
  const float* dt_b       = (const float*)d_in[8];
  const float* A_log      = (const float*)d_in[9];
  const float* D_skip     = (const float*)d_in[10];
  const float* W_out      = (const float*)d_in[11];
  const float* init_state = (const float*)d_in[12];
  const float* Wq         = (const float*)d_in[13];
  const float* Wk         = (const float*)d_in[14];
  const float* Wv         = (const float*)d_in[15];
  const float* bq         = (const float*)d_in[16];
  const float* bk         = (const float*)d_in[17];
  const float* bv         = (const float*)d_in[18];
  const float* Wo_attn    = (const float*)d_in[19];
  const float* bo         = (const float*)d_in[20];
  const float* ln_w       = (const float*)d_in[21];
  const float* ln_b       = (const float*)d_in[22];
  const float* head_w     = (const float*)d_in[23];
  float* ws = (float*)d_ws;
  float* out = (float*)d_out;

  // weight prep: transpose+convert to bf16 [N][K]
  hipLaunchKernelGGL(wtrans_k, dim3(15*8*32), dim3(256), 0, stream,
                     W_in, (u16*)(ws + OFF_WIT), 512, 2048, 8*32, 32);
  hipLaunchKernelGGL(wtrans_k, dim3(15*16*8), dim3(256), 0, stream,
                     W_out, (u16*)(ws + OFF_WOT), 1024, 512, 16*8, 8);
  hipLaunchKernelGGL(wtrans_k, dim3(15*16*1), dim3(256), 0, stream,
                     x_proj, (u16*)(ws + OFF_XPT), 1024, 64, 16*1, 1);

  int occ = 1;
  (void)hipOccupancyMaxActiveBlocksPerMultiprocessor(&occ, mamba_coop, 256, 0);
  if (occ < 1) occ = 1;
  if (occ > 2) occ = 2;
  const int grid = 256 * occ;

  void* args[] = { (void*)&tokens, (void*)&embed, (void*)&rms_w,
                   (void*)&conv_w, (void*)&conv_b, (void*)&dt_w,
                   (void*)&dt_b, (void*)&A_log, (void*)&D_skip,
                   (void*)&init_state, (void*)&ws };
  hipLaunchCooperativeKernel(reinterpret_cast<const void*>(&mamba_coop),
                             dim3(grid), dim3(256), args, 0, stream);

  hipLaunchKernelGGL(transpose_k, dim3(4096), dim3(256), 0, stream, Wq, Wk, Wv, Wo_attn, ws);
  hipLaunchKernelGGL(qkv_k, dim3(1056), dim3(256), 0, stream, bq, bk, bv, ws);
  hipLaunchKernelGGL(attn_k, dim3(4096), dim3(256), 0, stream, ws);
  hipLaunchKernelGGL(outproj_k, dim3(1024), dim3(256), 0, stream, bo, ws);
  hipLaunchKernelGGL(lnhead_k, dim3(1024), dim3(256), 0, stream, ln_w, ln_b, head_w, ws, out);
}

// Round 6
// 14493.341 us; speedup vs baseline: 1.7644x; 1.0999x over previous
//
#include <hip/hip_runtime.h>

typedef unsigned short u16;
typedef unsigned int u32;
typedef __attribute__((ext_vector_type(8))) short bf16x8;
typedef __attribute__((ext_vector_type(4))) float f32x4;

constexpr int BATCH = 2, SEQL = 2048, DMODEL = 512, DINNER = 1024;
constexpr int NLAYER = 15, BLKSZ = 64, NCHUNK = 32, TT = 65;
constexpr int NWG = 480;    // 15 layer-groups x 32 WGs

// ---- workspace layout (float units). Total 21,468,224 f = 85.9 MB ----
constexpr size_t OFF_H   = 0;          // [B*L][512] f32
constexpr size_t OFF_ST  = 2097152;    // [15][2][512] f32
constexpr size_t OFF_MEM = 2112512;    // [2][32][512] f32
constexpr size_t OFF_XZ  = 2145280;    // 15x[130][2048] f32 (x-half reused for dt)
constexpr size_t OFF_ANB = 6138880;    // 15x[144][512] bf16
constexpr size_t OFF_XCB = 6691840;    // 15x[160][1024] bf16
constexpr size_t OFF_YMB = 7920640;    // 15x[128][1024] bf16
constexpr size_t OFF_WIT = 8903680;    // 15x[2048][512] bf16
constexpr size_t OFF_WOT = 16768000;   // 15x[512][1024] bf16
constexpr size_t OFF_XPT = 20700160;   // 15x[64][1024] bf16
constexpr size_t OFF_DTW = 21191680;   // 15x[1024][32] bf16
constexpr size_t OFF_FLG = 21437440;   // 30720 stage flags + init counter
// attention region aliases coop scratch [OFF_XZ, OFF_WIT):
constexpr size_t OFF_Q   = 2145280;
constexpr size_t OFF_K   = 4242432;
constexpr size_t OFF_V   = 4275200;
constexpr size_t OFF_AO  = 4307968;    // ao doubles as hres
constexpr size_t OFF_WTA = 6405120;    // 4 x 262144 f32 attn W^T (ends 7,453,696)

__device__ __forceinline__ u16 f2b(float f) {
  u32 u = __builtin_bit_cast(u32, f);
  u = (u + 0x7fffu + ((u >> 16) & 1u)) >> 16;
  return (u16)u;
}
__device__ __forceinline__ float b2f(u16 u) {
  u32 v = ((u32)u) << 16;
  return __builtin_bit_cast(float, v);
}
__device__ __forceinline__ u32 pk2(float a, float b) {
  return (u32)f2b(a) | ((u32)f2b(b) << 16);
}

// ---- flag sync helpers (agent-scope release/acquire) ----
__device__ __forceinline__ void spin_until(int* f, int target) {
  int k = 0;
  while (__hip_atomic_load(f, __ATOMIC_RELAXED, __HIP_MEMORY_SCOPE_AGENT) < target) {
    __builtin_amdgcn_s_sleep(8);
    if (((++k) & 255) == 0)
      (void)__hip_atomic_load(f, __ATOMIC_ACQUIRE, __HIP_MEMORY_SCOPE_AGENT);
  }
  (void)__hip_atomic_load(f, __ATOMIC_ACQUIRE, __HIP_MEMORY_SCOPE_AGENT);
}
__device__ __forceinline__ void wait_flag(int* f, int target) {
  if (threadIdx.x == 0) spin_until(f, target);
  __syncthreads();
}
__device__ __forceinline__ void stage_bar(int* f, int target, bool arrive) {
  __syncthreads();   // prior stores drained before release
  if (threadIdx.x == 0) {
    if (arrive) __hip_atomic_fetch_add(f, 1, __ATOMIC_RELEASE, __HIP_MEMORY_SCOPE_AGENT);
    spin_until(f, target);
  }
  __syncthreads();
}

// ============================================================================
// Weight prep kernels.
// ============================================================================
__global__ void __launch_bounds__(256,2)
wtrans_k(const float* __restrict__ src, u16* __restrict__ dst,
         int R, int C, int tiles_rc, int tc)
{
  __shared__ float tile[64*65];
  const int mat = blockIdx.x / tiles_rc;
  const int rem = blockIdx.x % tiles_rc;
  const int r0 = (rem / tc) * 64, c0 = (rem % tc) * 64;
  const float* s = src + (size_t)mat * R * C;
  u16* d = dst + (size_t)mat * C * R;
  for (int i = threadIdx.x; i < 4096; i += 256) {
    const int r = i >> 6, cc = i & 63;
    tile[r*65 + cc] = s[(size_t)(r0 + r)*C + c0 + cc];
  }
  __syncthreads();
  for (int i = threadIdx.x; i < 4096; i += 256) {
    const int ci = i >> 6, rr = i & 63;
    d[(size_t)(c0 + ci)*R + r0 + rr] = f2b(tile[rr*65 + ci]);
  }
}

// dt_w [15][32][1024] f32 -> [15][1024][32] bf16
__global__ void __launch_bounds__(256,2)
dtwtrans_k(const float* __restrict__ src, u16* __restrict__ dst)
{
  const int i = blockIdx.x*256 + threadIdx.x;     // 15*32768
  const int jj = i >> 15, rem = i & 32767;
  const int d = rem >> 5, r = rem & 31;
  dst[i] = f2b(src[(size_t)jj*32768 + (size_t)r*1024 + d]);
}

// ============================================================================
// Persistent kernel: flag-pipelined (chunk, layer) stages. 480 WGs.
// No cooperative-groups dependency (init barrier is flag-based; FLG region is
// hipMemsetAsync-zeroed on the stream before launch).
// ============================================================================
__global__ void __launch_bounds__(256, 2)
mamba_coop(const int* __restrict__ tokens, const float* __restrict__ embed,
           const float* __restrict__ rms_w, const float* __restrict__ conv_w,
           const float* __restrict__ conv_b, const float* __restrict__ dt_b,
           const float* __restrict__ A_log, const float* __restrict__ D_skip,
           const float* __restrict__ init_state, float* __restrict__ ws)
{
  __shared__ __align__(16) float xd_lds[80*64];   // 20 KB
  float* h_  = ws + OFF_H;
  float* st_ = ws + OFF_ST;
  float* memb = ws + OFF_MEM;
  int* FLG = (int*)(ws + OFF_FLG);
  const int wg = blockIdx.x, tid = threadIdx.x;
  const int wv = tid >> 6, ln = tid & 63;
  const int lr = ln & 15, lq = ln >> 4;
  const int j = wg >> 5;        // layer group 0..14
  const int swg = wg & 31;      // slot within group

  // ---------- init: embedding gather + state init; flag barrier ----------
  {
    const int gtid = wg*256 + tid;
    const int gstr = NWG*256;
    for (int g = gtid; g < BATCH*SEQL*(DMODEL/8); g += gstr) {
      const int bl = g >> 6;
      const int m0 = (g & 63) << 3;
      const int tok = tokens[bl];
      const float* ep = embed + (size_t)tok*DMODEL + m0;
      float* hp = h_ + (size_t)bl*DMODEL + m0;
      *(float4*)hp     = *(const float4*)ep;
      *(float4*)(hp+4) = *(const float4*)(ep+4);
    }
    for (int i = gtid; i < NLAYER*BATCH*DMODEL; i += gstr) {
      const int m = i & (DMODEL-1);
      const int jj = i / (BATCH*DMODEL);
      st_[i] = init_state[jj*DMODEL + m];
    }
  }
  stage_bar(FLG + 30720, NWG, true);

  // per-layer pointers
  float* xz  = ws + OFF_XZ + (size_t)j*266240;     // x-half reused for dt after conv
  u16* anb = (u16*)(ws + OFF_ANB) + (size_t)j*73728;
  u16* xcb = (u16*)(ws + OFF_XCB) + (size_t)j*163840;
  u16* ymb = (u16*)(ws + OFF_YMB) + (size_t)j*131072;
  const u16* WiT = (const u16*)(ws + OFF_WIT) + (size_t)j*1048576;
  const u16* WoT = (const u16*)(ws + OFF_WOT) + (size_t)j*524288;
  const u16* XpT = (const u16*)(ws + OFF_XPT) + (size_t)j*65536;
  const u16* DwT = (const u16*)(ws + OFF_DTW) + (size_t)j*32768;
  const float* rw = rms_w + (size_t)j*DMODEL;
  const float* cvb = conv_b + (size_t)j*DINNER;
  const float* cww = conv_w + (size_t)j*DINNER*4;

  for (int c = 0; c < NCHUNK; ++c) {
    int* fs = FLG + ((c*15 + j)*4)*16;      // [phase]*16
    if (j > 0) wait_flag(FLG + ((c*15 + j-1)*4 + 3)*16, 32);

    // -------- PA: anb = bf16([state; rmsnorm(co)]), 144 rows --------
    for (int m = swg*4 + wv; m < 144; m += 128) {
      const int k0 = ln*8;
      uint4 pk;
      if (m < 130) {
        const int b = m/TT, t = m - b*TT;
        float v[8];
        if (t == 0) {
          const float* sp = st_ + ((size_t)j*BATCH + b)*DMODEL + k0;
          #pragma unroll
          for (int x = 0; x < 8; ++x) v[x] = sp[x];
        } else {
          const float* hp = h_ + (size_t)(b*SEQL + c*BLKSZ + t-1)*DMODEL + k0;
          const float4 v0 = *(const float4*)hp;
          const float4 v1 = *(const float4*)(hp+4);
          float ss = v0.x*v0.x + v0.y*v0.y + v0.z*v0.z + v0.w*v0.w
                   + v1.x*v1.x + v1.y*v1.y + v1.z*v1.z + v1.w*v1.w;
          #pragma unroll
          for (int off = 32; off > 0; off >>= 1) ss += __shfl_xor(ss, off);
          const float rs = rsqrtf(ss * (1.f/512.f) + 1e-6f);
          const float o[8] = {v0.x,v0.y,v0.z,v0.w,v1.x,v1.y,v1.z,v1.w};
          #pragma unroll
          for (int x = 0; x < 8; ++x) v[x] = o[x] * rs * rw[k0 + x];
        }
        pk = make_uint4(pk2(v[0],v[1]), pk2(v[2],v[3]), pk2(v[4],v[5]), pk2(v[6],v[7]));
      } else {
        pk = make_uint4(0,0,0,0);
      }
      *(uint4*)(anb + (size_t)m*512 + k0) = pk;
    }
    stage_bar(fs + 0*16, 32, true);

    // -------- PB: xz = anb @ W_inT (130x2048,K=512); nb = swg; fused conv ---
    {
      const int nb = swg;
      const int n_base = nb*64;
      f32x4 acc[3][4] = {};
      for (int kk = 0; kk < 16; ++kk) {
        const int k0 = kk*32 + lq*8;
        bf16x8 bf[4];
        #pragma unroll
        for (int nt = 0; nt < 4; ++nt)
          bf[nt] = *(const bf16x8*)(WiT + (size_t)(n_base + nt*16 + lr)*512 + k0);
        #pragma unroll
        for (int i = 0; i < 3; ++i) {
          if (i == 2 && wv != 0) continue;
          const int mt = wv + 4*i;
          const bf16x8 af = *(const bf16x8*)(anb + (size_t)(mt*16 + lr)*512 + k0);
          #pragma unroll
          for (int nt = 0; nt < 4; ++nt)
            acc[i][nt] = __builtin_amdgcn_mfma_f32_16x16x32_bf16(af, bf[nt], acc[i][nt], 0, 0, 0);
        }
      }
      #pragma unroll
      for (int i = 0; i < 3; ++i) {
        if (i == 2 && wv != 0) continue;
        const int mt = wv + 4*i;
        #pragma unroll
        for (int nt = 0; nt < 4; ++nt)
          #pragma unroll
          for (int r = 0; r < 4; ++r) {
            const int m = mt*16 + lq*4 + r;
            if (m < 130)
              xz[(size_t)m*2048 + n_base + nt*16 + lr] = acc[i][nt][r];
          }
      }
      if (nb < 16) {    // conv+silu epilogue, WG-local columns -> xcb (bf16)
        __syncthreads();
        for (int e = tid; e < 64*160; e += 256) {
          const int d = n_base + (e & 63);
          const int row2 = e >> 6;
          const int b = row2 / 80, t = row2 - b*80;
          if (t < TT) {
            float a = cvb[d];
            #pragma unroll
            for (int q = 0; q < 4; ++q) {
              const int tt = t - 3 + q;
              if (tt >= 0) a = fmaf(xz[(size_t)(b*TT+tt)*2048 + d], cww[d*4+q], a);
            }
            const float sv = a / (1.f + __expf(-a));
            xcb[(size_t)row2*1024 + d] = f2b(sv);
          } else {
            xcb[(size_t)row2*1024 + d] = 0;
          }
        }
      }
    }
    stage_bar(fs + 1*16, 32, true);

    // -------- PD (swg<8): xd GEMM -> LDS; dt GEMM (K=32) -> xz x-half; scan -
    if (swg < 8) {
      const int p = swg, b = p >> 2, slice = p & 3;
      const u16* xa = xcb + (size_t)b*80*1024;
      for (int mt = 0; mt < 5; ++mt) {
        f32x4 acc = {};
        for (int kk = 0; kk < 32; ++kk) {
          const int k0 = kk*32 + lq*8;
          const bf16x8 af = *(const bf16x8*)(xa + (size_t)(mt*16 + lr)*1024 + k0);
          const bf16x8 bf = *(const bf16x8*)(XpT + (size_t)(wv*16 + lr)*1024 + k0);
          acc = __builtin_amdgcn_mfma_f32_16x16x32_bf16(af, bf, acc, 0, 0, 0);
        }
        #pragma unroll
        for (int r = 0; r < 4; ++r)
          xd_lds[(mt*16 + lq*4 + r)*64 + wv*16 + lr] = acc[r];
      }
      __syncthreads();
      // dt GEMM: dt[t, d-slice] = softplus(xd[t,:32] @ DwT + dt_b) -> xz x-half
      for (int ni = 0; ni < 4; ++ni) {
        const int n0 = (slice*16 + wv*4 + ni)*16;
        const bf16x8 bf = *(const bf16x8*)(DwT + (size_t)(n0 + lr)*32 + lq*8);
        const float dtbv_l = dt_b[(size_t)j*DINNER + n0 + lr];
        for (int mt = 0; mt < 5; ++mt) {
          bf16x8 af;
          #pragma unroll
          for (int x = 0; x < 8; ++x)
            af[x] = (short)f2b(xd_lds[(mt*16 + lr)*64 + lq*8 + x]);
          f32x4 acc = {};
          acc = __builtin_amdgcn_mfma_f32_16x16x32_bf16(af, bf, acc, 0, 0, 0);
          #pragma unroll
          for (int r = 0; r < 4; ++r) {
            const int m = mt*16 + lq*4 + r;
            if (m < TT) {
              const float v = acc[r] + dtbv_l;
              const float sp = (v > 15.f) ? v : log1pf(__expf(v));
              xz[((size_t)b*TT + m)*2048 + n0 + lr] = sp;   // dt into dead x-half
            }
          }
        }
      }
      __syncthreads();
      // scan: one thread per d in slice
      {
        const int d = slice*256 + tid;
        float Ai[16], s[16];
        const float* alp = A_log + (size_t)j*DINNER*16 + (size_t)d*16;
        #pragma unroll
        for (int i = 0; i < 16; ++i) { Ai[i] = -__expf(alp[i]); s[i] = 0.f; }
        const float Dv = D_skip[(size_t)j*DINNER + d];
        const float* dtp = xz + (size_t)b*TT*2048 + d;          // dt (x-half)
        const u16*   xcp = xcb + (size_t)b*80*1024 + d;
        const float* xzp = xz + (size_t)b*TT*2048 + 1024 + d;   // z (z-half)
        u16* ymp = ymb + (size_t)b*64*1024 + d;
        for (int t = 0; t < TT; ++t) {
          const float dt_ = dtp[(size_t)t*2048];
          const float xcv = b2f(xcp[(size_t)t*1024]);
          const float zv  = xzp[(size_t)t*2048];
          const float u = dt_ * xcv;
          const float4* row = (const float4*)(xd_lds + t*64 + 32);
          float y0 = 0.f, y1 = 0.f, y2 = 0.f, y3 = 0.f;
          #pragma unroll
          for (int i = 0; i < 4; ++i) {
            const float4 Bv = row[i];
            const float4 Cv = row[4+i];
            float P;
            P = __expf(dt_*Ai[4*i+0]); s[4*i+0] = fmaf(s[4*i+0], P, u*Bv.x); y0 = fmaf(s[4*i+0], Cv.x, y0);
            P = __expf(dt_*Ai[4*i+1]); s[4*i+1] = fmaf(s[4*i+1], P, u*Bv.y); y1 = fmaf(s[4*i+1], Cv.y, y1);
            P = __expf(dt_*Ai[4*i+2]); s[4*i+2] = fmaf(s[4*i+2], P, u*Bv.z); y2 = fmaf(s[4*i+2], Cv.z, y2);
            P = __expf(dt_*Ai[4*i+3]); s[4*i+3] = fmaf(s[4*i+3], P, u*Bv.w); y3 = fmaf(s[4*i+3], Cv.w, y3);
          }
          const float sz = zv / (1.f + __expf(-zv));
          if (t >= 1)
            ymp[(size_t)(t-1)*1024] = f2b(((y0+y1)+(y2+y3) + Dv*xcv) * sz);
        }
      }
    }
    stage_bar(fs + 2*16, 8, swg < 8);

    // -------- PE: lo = ymb @ W_outT (128x512,K=1024); h+=, state/mem --------
    {
      const int nt0 = swg;
      f32x4 acc[2] = {};
      for (int kk = 0; kk < 32; ++kk) {
        const int k0 = kk*32 + lq*8;
        const bf16x8 bf = *(const bf16x8*)(WoT + (size_t)(nt0*16 + lr)*1024 + k0);
        #pragma unroll
        for (int i = 0; i < 2; ++i) {
          const int mt = wv*2 + i;
          const bf16x8 af = *(const bf16x8*)(ymb + (size_t)(mt*16 + lr)*1024 + k0);
          acc[i] = __builtin_amdgcn_mfma_f32_16x16x32_bf16(af, bf, acc[i], 0, 0, 0);
        }
      }
      const int col = nt0*16 + lr;
      #pragma unroll
      for (int i = 0; i < 2; ++i) {
        const int mt = wv*2 + i;
        #pragma unroll
        for (int r = 0; r < 4; ++r) {
          const int m = mt*16 + lq*4 + r;
          const int b = m >> 6, tm = m & 63;
          const float v = acc[i][r];
          float* hp = h_ + (size_t)(b*SEQL + c*BLKSZ + tm)*DMODEL + col;
          *hp += v;
          if (tm == 63) {
            st_[((size_t)j*BATCH + b)*DMODEL + col] = v;
            if (j == NLAYER-1)
              memb[((size_t)b*NCHUNK + c)*DMODEL + col] = v;
          }
        }
      }
    }
    stage_bar(fs + 3*16, 32, true);
  }
}

// ============================================================================
// Post kernels.
// ============================================================================
__global__ void __launch_bounds__(256,1)
transpose_k(const float* __restrict__ wq, const float* __restrict__ wk,
            const float* __restrict__ wvm, const float* __restrict__ wo,
            float* __restrict__ ws)
{
  float* wt = ws + OFF_WTA;
  const float* srcs[4] = { wq, wk, wvm, wo };
  const int which = blockIdx.x >> 10;
  const int idx = ((blockIdx.x & 1023) << 8) + threadIdx.x;
  const int o = idx >> 9, m = idx & 511;
  wt[(size_t)which*262144 + (size_t)m*512 + o] = srcs[which][(size_t)o*512 + m];
}

__global__ void __launch_bounds__(256,1)
qkv_k(const float* __restrict__ bq, const float* __restrict__ bk, const float* __restrict__ bv,
      float* __restrict__ ws)
{
  __shared__ __align__(16) float lds[8192];
  const float* wt = ws + OFF_WTA;
  const int wg = blockIdx.x, tid = threadIdx.x;
  const int rtg = wg >> 2, ct = wg & 3;
  const float* A; const float* Bm; const float* bias; float* out; int m0;
  if (rtg < 256)      { A = ws+OFF_H;   Bm = wt;          bias = bq; out = ws+OFF_Q; m0 = rtg*16; }
  else if (rtg < 260) { A = ws+OFF_MEM; Bm = wt + 262144; bias = bk; out = ws+OFF_K; m0 = (rtg-256)*16; }
  else                { A = ws+OFF_MEM; Bm = wt + 524288; bias = bv; out = ws+OFF_V; m0 = (rtg-260)*16; }
  for (int i = tid; i < 2048; i += 256) {
    const int f = i*4;
    *(float4*)(lds+f) = *(const float4*)(A + (size_t)(m0 + (f>>9))*512 + (f & 511));
  }
  __syncthreads();
  const int col0 = ct*128 + (tid & 63)*2;
  const int rq = tid >> 6;
  const float2* wp2 = (const float2*)(Bm + col0);
  const float* ap = lds + rq*2048;
  float acc0[4] = {0,0,0,0}, acc1[4] = {0,0,0,0};
  for (int k = 0; k < 512; k += 4) {
    const float2 w0 = wp2[(size_t)(k+0)*256];
    const float2 w1 = wp2[(size_t)(k+1)*256];
    const float2 w2 = wp2[(size_t)(k+2)*256];
    const float2 w3 = wp2[(size_t)(k+3)*256];
    #pragma unroll
    for (int r4 = 0; r4 < 4; ++r4) {
      const float4 a = *(const float4*)(ap + r4*512 + k);
      acc0[r4] = fmaf(a.x, w0.x, acc0[r4]); acc1[r4] = fmaf(a.x, w0.y, acc1[r4]);
      acc0[r4] = fmaf(a.y, w1.x, acc0[r4]); acc1[r4] = fmaf(a.y, w1.y, acc1[r4]);
      acc0[r4] = fmaf(a.z, w2.x, acc0[r4]); acc1[r4] = fmaf(a.z, w2.y, acc1[r4]);
      acc0[r4] = fmaf(a.w, w3.x, acc0[r4]); acc1[r4] = fmaf(a.w, w3.y, acc1[r4]);
    }
  }
  const float bb0 = bias[col0], bb1 = bias[col0+1];
  #pragma unroll
  for (int r4 = 0; r4 < 4; ++r4)
    *(float2*)(out + (size_t)(m0 + rq*4 + r4)*512 + col0) = make_float2(acc0[r4]+bb0, acc1[r4]+bb1);
}

__global__ void __launch_bounds__(256,1)
attn_k(float* __restrict__ ws)
{
  const float* q  = ws + OFF_Q;
  const float* kk = ws + OFF_K;
  const float* vvv = ws + OFF_V;
  float* ao = ws + OFF_AO;
  const int gw = (blockIdx.x*256 + threadIdx.x) >> 6;
  const int ln = threadIdx.x & 63;
  const int l = gw & (SEQL-1);
  const int bh = gw >> 11;
  const int b = bh >> 2, hh = bh & 3;
  const int tb = l >> 6;
  float* aop = ao + (size_t)(b*SEQL + l)*512 + hh*128;
  if (tb == 0) { *(float2*)(aop + ln*2) = make_float2(0.f, 0.f); return; }
  float sc = -1e30f;
  if (ln < tb) {
    const float* qp = q + (size_t)(b*SEQL+l)*512 + hh*128;
    const float* kp = kk + (size_t)(b*NCHUNK+ln)*512 + hh*128;
    float s = 0.f;
    for (int dd = 0; dd < 128; dd += 4) {
      const float4 qq = *(const float4*)(qp+dd);
      const float4 kv = *(const float4*)(kp+dd);
      s += qq.x*kv.x + qq.y*kv.y + qq.z*kv.z + qq.w*kv.w;
    }
    sc = s * 0.08838834764831845f;
  }
  float mx = sc;
  #pragma unroll
  for (int off = 32; off > 0; off >>= 1) mx = fmaxf(mx, __shfl_xor(mx, off));
  const float w = (ln < tb) ? __expf(sc - mx) : 0.f;
  float sm = w;
  #pragma unroll
  for (int off = 32; off > 0; off >>= 1) sm += __shfl_xor(sm, off);
  const float inv = 1.f / sm;
  float a0 = 0.f, a1 = 0.f;
  const int d0 = ln*2;
  for (int mm = 0; mm < tb; ++mm) {
    const float am = __shfl(w, mm) * inv;
    const float2 vp = *(const float2*)(vvv + (size_t)(b*NCHUNK+mm)*512 + hh*128 + d0);
    a0 = fmaf(am, vp.x, a0);
    a1 = fmaf(am, vp.y, a1);
  }
  *(float2*)(aop + d0) = make_float2(a0, a1);
}

__global__ void __launch_bounds__(256,1)
outproj_k(const float* __restrict__ bo, float* __restrict__ ws)
{
  __shared__ __align__(16) float lds[8192];
  float* ao  = ws + OFF_AO;
  const float* woT = ws + OFF_WTA + 786432;
  const float* h_ = ws + OFF_H;
  const int wg = blockIdx.x, tid = threadIdx.x;
  const int rtg = wg >> 2, ct = wg & 3;
  const int m0 = rtg*16;
  for (int i = tid; i < 2048; i += 256) {
    const int f = i*4;
    *(float4*)(lds+f) = *(const float4*)(ao + (size_t)(m0 + (f>>9))*512 + (f & 511));
  }
  __syncthreads();
  const int col0 = ct*128 + (tid & 63)*2;
  const int rq = tid >> 6;
  const float2* wp2 = (const float2*)(woT + col0);
  const float* ap = lds + rq*2048;
  float acc0[4] = {0,0,0,0}, acc1[4] = {0,0,0,0};
  for (int k = 0; k < 512; k += 4) {
    const float2 w0 = wp2[(size_t)(k+0)*256];
    const float2 w1 = wp2[(size_t)(k+1)*256];
    const float2 w2 = wp2[(size_t)(k+2)*256];
    const float2 w3 = wp2[(size_t)(k+3)*256];
    #pragma unroll
    for (int r4 = 0; r4 < 4; ++r4) {
      const float4 a = *(const float4*)(ap + r4*512 + k);
      acc0[r4] = fmaf(a.x, w0.x, acc0[r4]); acc1[r4] = fmaf(a.x, w0.y, acc1[r4]);
      acc0[r4] = fmaf(a.y, w1.x, acc0[r4]); acc1[r4] = fmaf(a.y, w1.y, acc1[r4]);
      acc0[r4] = fmaf(a.z, w2.x, acc0[r4]); acc1[r4] = fmaf(a.z, w2.y, acc1[r4]);
      acc0[r4] = fmaf(a.w, w3.x, acc0[r4]); acc1[r4] = fmaf(a.w, w3.y, acc1[r4]);
    }
  }
  const float bb0 = bo[col0], bb1 = bo[col0+1];
  #pragma unroll
  for (int r4 = 0; r4 < 4; ++r4) {
    const int m = m0 + rq*4 + r4;
    const float hp = ((m & (SEQL-1)) >= BLKSZ) ? 1.f : 0.f;
    const float2 hv = *(const float2*)(h_ + (size_t)m*512 + col0);
    *(float2*)(ao + (size_t)m*512 + col0) =
        make_float2(hv.x + (acc0[r4]+bb0)*hp, hv.y + (acc1[r4]+bb1)*hp);
  }
}

__global__ void __launch_bounds__(256,1)
lnhead_k(const float* __restrict__ lnw, const float* __restrict__ lnb,
         const float* __restrict__ head_w, float* __restrict__ ws, float* __restrict__ out)
{
  __shared__ __align__(16) float lds[8192];
  const float* hres = ws + OFF_AO;
  const int wg = blockIdx.x, tid = threadIdx.x;
  const int wv = tid >> 6, ln = tid & 63;
  const int rtg = wg >> 2, ct = wg & 3;
  const int m0 = rtg*16;
  for (int r = wv; r < 16; r += 4) {
    const float* src = hres + (size_t)(m0+r)*512 + ln*8;
    const float4 v0 = *(const float4*)src;
    const float4 v1 = *(const float4*)(src+4);
    float s1 = v0.x+v0.y+v0.z+v0.w + v1.x+v1.y+v1.z+v1.w;
    float s2 = v0.x*v0.x+v0.y*v0.y+v0.z*v0.z+v0.w*v0.w
             + v1.x*v1.x+v1.y*v1.y+v1.z*v1.z+v1.w*v1.w;
    #pragma unroll
    for (int off = 32; off > 0; off >>= 1) { s1 += __shfl_xor(s1, off); s2 += __shfl_xor(s2, off); }
    const float mu = s1 * (1.f/512.f);
    const float var = fmaxf(s2 * (1.f/512.f) - mu*mu, 0.f);
    const float nf = rsqrtf(var + 1e-5f);
    const float o[8] = {v0.x,v0.y,v0.z,v0.w,v1.x,v1.y,v1.z,v1.w};
    #pragma unroll
    for (int x = 0; x < 8; ++x)
      lds[r*512 + ln*8 + x] = (o[x]-mu)*nf*lnw[ln*8+x] + lnb[ln*8+x];
  }
  __syncthreads();
  const int col0 = ct*128 + (tid & 63)*2;
  const int rq = tid >> 6;
  const float2* wp2 = (const float2*)(head_w + col0);
  const float* ap = lds + rq*2048;
  float acc0[4] = {0,0,0,0}, acc1[4] = {0,0,0,0};
  for (int k = 0; k < 512; k += 4) {
    const float2 w0 = wp2[(size_t)(k+0)*256];
    const float2 w1 = wp2[(size_t)(k+1)*256];
    const float2 w2 = wp2[(size_t)(k+2)*256];
    const float2 w3 = wp2[(size_t)(k+3)*256];
    #pragma unroll
    for (int r4 = 0; r4 < 4; ++r4) {
      const float4 a = *(const float4*)(ap + r4*512 + k);
      acc0[r4] = fmaf(a.x, w0.x, acc0[r4]); acc1[r4] = fmaf(a.x, w0.y, acc1[r4]);
      acc0[r4] = fmaf(a.y, w1.x, acc0[r4]); acc1[r4] = fmaf(a.y, w1.y, acc1[r4]);
      acc0[r4] = fmaf(a.z, w2.x, acc0[r4]); acc1[r4] = fmaf(a.z, w2.y, acc1[r4]);
      acc0[r4] = fmaf(a.w, w3.x, acc0[r4]); acc1[r4] = fmaf(a.w, w3.y, acc1[r4]);
    }
  }
  #pragma unroll
  for (int r4 = 0; r4 < 4; ++r4) {
    const size_t oi = (size_t)(m0 + rq*4 + r4)*512 + col0;
    *(float2*)(out + oi) = make_float2(acc0[r4], acc1[r4]);
  }
}

extern "C" void kernel_launch(void* const* d_in, const int* in_sizes, int n_in,
                              void* d_out, int out_size, void* d_ws, size_t ws_size,
                              hipStream_t stream)
{
  const int*   tokens     = (const int*)d_in[0];
  const float* embed      = (const float*)d_in[1];
  const float* rms_w      = (const float*)d_in[2];
  const float* W_in       = (const float*)d_in[3];
  const float* conv_w     = (const float*)d_in[4];
  const float* conv_b     = (const float*)d_in[5];
  const float* x_proj     = (const float*)d_in[6];
  const float* dt_w       = (const float*)d_in[7];
  const float* dt_b       = (const float*)d_in[8];
  const float* A_log      = (const float*)d_in[9];
  const float* D_skip     = (const float*)d_in[10];
  const float* W_out      = (const float*)d_in[11];
  const float* init_state = (const float*)d_in[12];
  const float* Wq         = (const float*)d_in[13];
  const float* Wk         = (const float*)d_in[14];
  const float* Wv         = (const float*)d_in[15];
  const float* bq         = (const float*)d_in[16];
  const float* bk         = (const float*)d_in[17];
  const float* bv         = (const float*)d_in[18];
  const float* Wo_attn    = (const float*)d_in[19];
  const float* bo         = (const float*)d_in[20];
  const float* ln_w       = (const float*)d_in[21];
  const float* ln_b       = (const float*)d_in[22];
  const float* head_w     = (const float*)d_in[23];
  float* ws = (float*)d_ws;
  float* out = (float*)d_out;

  // weight prep
  hipLaunchKernelGGL(wtrans_k, dim3(15*8*32), dim3(256), 0, stream,
                     W_in, (u16*)(ws + OFF_WIT), 512, 2048, 8*32, 32);
  hipLaunchKernelGGL(wtrans_k, dim3(15*16*8), dim3(256), 0, stream,
                     W_out, (u16*)(ws + OFF_WOT), 1024, 512, 16*8, 8);
  hipLaunchKernelGGL(wtrans_k, dim3(15*16*1), dim3(256), 0, stream,
                     x_proj, (u16*)(ws + OFF_XPT), 1024, 64, 16*1, 1);
  hipLaunchKernelGGL(dtwtrans_k, dim3(15*128), dim3(256), 0, stream,
                     dt_w, (u16*)(ws + OFF_DTW));

  // zero the flag region (incl. init counter) on-stream
  (void)hipMemsetAsync(ws + OFF_FLG, 0, (30720 + 64) * sizeof(int), stream);

  void* args[] = { (void*)&tokens, (void*)&embed, (void*)&rms_w,
                   (void*)&conv_w, (void*)&conv_b, (void*)&dt_b,
                   (void*)&A_log, (void*)&D_skip, (void*)&init_state, (void*)&ws };
  hipError_t cerr = hipLaunchCooperativeKernel(
      reinterpret_cast<const void*>(&mamba_coop),
      dim3(NWG), dim3(256), args, 0, stream);
  if (cerr != hipSuccess) {
    // fallback: plain persistent launch (co-residency via launch_bounds occupancy)
    hipLaunchKernelGGL(mamba_coop, dim3(NWG), dim3(256), 0, stream,
                       tokens, embed, rms_w, conv_w, conv_b, dt_b,
                       A_log, D_skip, init_state, ws);
  }

  hipLaunchKernelGGL(transpose_k, dim3(4096), dim3(256), 0, stream, Wq, Wk, Wv, Wo_attn, ws);
  hipLaunchKernelGGL(qkv_k, dim3(1056), dim3(256), 0, stream, bq, bk, bv, ws);
  hipLaunchKernelGGL(attn_k, dim3(4096), dim3(256), 0, stream, ws);
  hipLaunchKernelGGL(outproj_k, dim3(1024), dim3(256), 0, stream, bo, ws);
  hipLaunchKernelGGL(lnhead_k, dim3(1024), dim3(256), 0, stream, ln_w, ln_b, head_w, ws, out);
}